// Round 1
// baseline (1440.846 us; speedup 1.0000x reference)
//
#include <hip/hip_runtime.h>

typedef unsigned short ushort_t;
typedef __attribute__((ext_vector_type(8))) short bf16x8;
typedef __attribute__((ext_vector_type(4))) float f32x4;

#define DECAY 0.99f
#define EPS 1e-5f
#define K_CODES 1024
#define D 512
#define N_ROWS 65536
#define MARGIN 0.0625f

// MFMA vq_main tiling: block = 128 rows x 128 codes, BK=32, 4 waves (2x2).
#define BM 128
#define NKT 8          // K_CODES / 128
#define NCH 16         // D / 32 chunks

// ws layout (bytes)
#define XH_OFF   0u
#define XL_OFF   67108864u
#define EH_OFF   134217728u
#define EL_OFF   135266304u
#define ESUM_OFF 136314880u
#define CNT_OFF  138412032u
#define E2_OFF   138416128u
#define NFLAG_OFF 138420224u
#define NPTR_OFF  138420228u
#define FLAGS_OFF 138420480u
#define WS_NEED  (138420480u + 262144u)

// ---------------------------------------------------------------------------
__device__ inline ushort_t f2bf(float f) {
    unsigned int u = __float_as_uint(f);
    unsigned int r = (u + 0x7FFFu + ((u >> 16) & 1u)) >> 16;
    return (ushort_t)r;
}
__device__ inline float bf2f(ushort_t h) { return __uint_as_float(((unsigned int)h) << 16); }

__device__ inline void gload16_lds(const void* g, void* l) {
    __builtin_amdgcn_global_load_lds(
        (const __attribute__((address_space(1))) unsigned int*)g,
        (__attribute__((address_space(3))) unsigned int*)l, 16, 0, 0);
}

// ---------------------------------------------------------------------------
// Split src (f32, rows x 512) into bf16 hi/lo planes in MFMA-fragment-tiled
// order: linear = ((rowtile*16 + kchunk)*64 + lane)*8 + j, where
// lane = (row&15) + 16*((k>>3)&3), j = k&7.  One thread per 8 elements,
// thread id == output frag slot -> coalesced 16B writes, 32B-chunk reads.
__global__ __launch_bounds__(256) void prep_split(const float* __restrict__ src,
                                                  ushort_t* __restrict__ hi,
                                                  ushort_t* __restrict__ lo) {
    const int g = blockIdx.x * 256 + threadIdx.x;
    const int ln = g & 63;
    const int tc = g >> 6;
    const int C = tc & 15;
    const int R = tc >> 4;
    const int row = (R << 4) + (ln & 15);
    const int k = (C << 5) + ((ln >> 4) << 3);
    const float4 v0 = *(const float4*)(src + (size_t)row * D + k);
    const float4 v1 = *(const float4*)(src + (size_t)row * D + k + 4);
    float v[8] = {v0.x, v0.y, v0.z, v0.w, v1.x, v1.y, v1.z, v1.w};
    short h[8], l[8];
    #pragma unroll
    for (int i = 0; i < 8; ++i) {
        ushort_t hh = f2bf(v[i]);
        h[i] = (short)hh;
        l[i] = (short)f2bf(v[i] - bf2f(hh));
    }
    bf16x8 hv = {h[0], h[1], h[2], h[3], h[4], h[5], h[6], h[7]};
    bf16x8 lv = {l[0], l[1], l[2], l[3], l[4], l[5], l[6], l[7]};
    *(bf16x8*)(hi + (size_t)g * 8) = hv;
    *(bf16x8*)(lo + (size_t)g * 8) = lv;
}

// ---------------------------------------------------------------------------
__global__ __launch_bounds__(64) void e2_kernel(const float* __restrict__ embed,
                                                float* __restrict__ e2) {
    const int k = blockIdx.x;
    const int t = threadIdx.x;
    const float* row = embed + (size_t)k * D;
    float s = 0.f;
    #pragma unroll
    for (int i = 0; i < D / 64; ++i) {
        float v = row[t + 64 * i];
        s = fmaf(v, v, s);
    }
    #pragma unroll
    for (int off = 32; off; off >>= 1) s += __shfl_down(s, off, 64);
    if (t == 0) e2[k] = s;
}

// ---------------------------------------------------------------------------
// MFMA distance + argmax(top2) + quantize + scatter.
// score = dot(x,e) - 0.5*|e|^2, dot via bf16 hh+hl+lh in fp32 accumulator.
__global__ __launch_bounds__(256, 2) void vq_main(const ushort_t* __restrict__ xh,
                                                  const ushort_t* __restrict__ xl,
                                                  const ushort_t* __restrict__ eh,
                                                  const ushort_t* __restrict__ el,
                                                  const float* __restrict__ x,
                                                  const float* __restrict__ embed,
                                                  const float* __restrict__ e2,
                                                  float* __restrict__ out_q,
                                                  float* __restrict__ out_ind,
                                                  float* __restrict__ counts,
                                                  float* __restrict__ embed_sum,
                                                  int* __restrict__ nflag,
                                                  int* __restrict__ flags) {
    __shared__ short sAh[4096], sAl[4096], sBh[4096], sBl[4096];  // 8KB each
    __shared__ float se2[1024];
    __shared__ float red_b[128][2], red_s[128][2];
    __shared__ int   red_i[128][2];
    __shared__ int   bestk[128];

    const int tid = threadIdx.x;
    const int lane = tid & 63;
    const int w = tid >> 6;
    const int wm = w & 1;       // wave row half
    const int wn = w >> 1;      // wave col half
    const int R0 = blockIdx.x * 8;   // row-tile base (8 row-tiles of 16)
    const int row0 = blockIdx.x * BM;

    for (int i = tid; i < 1024; i += 256) se2[i] = e2[i];

    // staging assignment: wave w stages 8 tiles of one plane
    const int ltile = lane << 3;  // lane*8 shorts = lane*16 B

    float tb[16], ts[16];
    int ti[16];
    #pragma unroll
    for (int s = 0; s < 16; ++s) { tb[s] = -3.4e38f; ts[s] = -3.4e38f; ti[s] = 0; }

    for (int kt = 0; kt < NKT; ++kt) {
        f32x4 acc[4][4];
        #pragma unroll
        for (int mt = 0; mt < 4; ++mt)
            #pragma unroll
            for (int nt = 0; nt < 4; ++nt) acc[mt][nt] = (f32x4){0.f, 0.f, 0.f, 0.f};

        for (int c = 0; c < NCH; ++c) {
            __syncthreads();
            // stage 32 KB: wave 0 -> Ah, 1 -> Al, 2 -> Bh, 3 -> Bl (8 tiles each)
            if (w == 0) {
                #pragma unroll
                for (int t = 0; t < 8; ++t)
                    gload16_lds(xh + ((size_t)((R0 + t) * 16 + c) << 9) + ltile, sAh + (t << 9));
            } else if (w == 1) {
                #pragma unroll
                for (int t = 0; t < 8; ++t)
                    gload16_lds(xl + ((size_t)((R0 + t) * 16 + c) << 9) + ltile, sAl + (t << 9));
            } else if (w == 2) {
                #pragma unroll
                for (int t = 0; t < 8; ++t)
                    gload16_lds(eh + ((size_t)(((kt << 3) + t) * 16 + c) << 9) + ltile, sBh + (t << 9));
            } else {
                #pragma unroll
                for (int t = 0; t < 8; ++t)
                    gload16_lds(el + ((size_t)(((kt << 3) + t) * 16 + c) << 9) + ltile, sBl + (t << 9));
            }
            __syncthreads();

            bf16x8 ah[4], al4[4], bh[4], bl[4];
            #pragma unroll
            for (int i = 0; i < 4; ++i) {
                ah[i]  = *(const bf16x8*)(sAh + (((wm << 2) + i) << 9) + ltile);
                al4[i] = *(const bf16x8*)(sAl + (((wm << 2) + i) << 9) + ltile);
                bh[i]  = *(const bf16x8*)(sBh + (((wn << 2) + i) << 9) + ltile);
                bl[i]  = *(const bf16x8*)(sBl + (((wn << 2) + i) << 9) + ltile);
            }
            #pragma unroll
            for (int nt = 0; nt < 4; ++nt) {
                #pragma unroll
                for (int mt = 0; mt < 4; ++mt) {
                    acc[mt][nt] = __builtin_amdgcn_mfma_f32_16x16x32_bf16(ah[mt], bh[nt], acc[mt][nt], 0, 0, 0);
                    acc[mt][nt] = __builtin_amdgcn_mfma_f32_16x16x32_bf16(al4[mt], bh[nt], acc[mt][nt], 0, 0, 0);
                    acc[mt][nt] = __builtin_amdgcn_mfma_f32_16x16x32_bf16(ah[mt], bl[nt], acc[mt][nt], 0, 0, 0);
                }
            }
        }

        // fold scores of this kt's 64 wave-local codes into per-row top2
        #pragma unroll
        for (int nt = 0; nt < 4; ++nt) {
            const int code = (kt << 7) + (wn << 6) + (nt << 4) + (lane & 15);
            const float h = se2[code];
            #pragma unroll
            for (int mt = 0; mt < 4; ++mt) {
                #pragma unroll
                for (int r = 0; r < 4; ++r) {
                    const float v = fmaf(-0.5f, h, acc[mt][nt][r]);
                    const int s = (mt << 2) + r;
                    if (v > tb[s]) { ts[s] = tb[s]; tb[s] = v; ti[s] = code; }
                    else if (v > ts[s]) ts[s] = v;
                }
            }
        }
    }

    // butterfly merge across the 16 col-lanes (same rows)
    #pragma unroll
    for (int m = 1; m <= 8; m <<= 1) {
        #pragma unroll
        for (int s = 0; s < 16; ++s) {
            const float ob = __shfl_xor(tb[s], m, 64);
            const float os = __shfl_xor(ts[s], m, 64);
            const int oi = __shfl_xor(ti[s], m, 64);
            if (ob > tb[s] || (ob == tb[s] && oi < ti[s])) {
                ts[s] = fmaxf(tb[s], os); tb[s] = ob; ti[s] = oi;
            } else {
                ts[s] = fmaxf(ts[s], ob);
            }
        }
    }
    if ((lane & 15) == 0) {
        const int q = lane >> 4;
        #pragma unroll
        for (int mt = 0; mt < 4; ++mt)
            #pragma unroll
            for (int r = 0; r < 4; ++r) {
                const int rl = wm * 64 + mt * 16 + q * 4 + r;
                const int s = (mt << 2) + r;
                red_b[rl][wn] = tb[s]; red_s[rl][wn] = ts[s]; red_i[rl][wn] = ti[s];
            }
    }
    __syncthreads();

    if (tid < BM) {
        float b0 = red_b[tid][0], b1 = red_b[tid][1];
        float s0 = red_s[tid][0], s1 = red_s[tid][1];
        int i0 = red_i[tid][0], i1 = red_i[tid][1];
        float b, sec; int bi;
        if (b0 > b1 || (b0 == b1 && i0 < i1)) { b = b0; bi = i0; sec = fmaxf(s0, b1); }
        else { b = b1; bi = i1; sec = fmaxf(s1, b0); }
        bestk[tid] = bi;
        out_ind[row0 + tid] = (float)bi;
        atomicAdd(counts + bi, 1.0f);
        if (b - sec < MARGIN) {
            const int p = atomicAdd(nflag, 1);
            flags[p] = row0 + tid;
        }
    }
    __syncthreads();

    // quantize gather + embed_sum scatter (128 threads per row, coalesced)
    {
        const int f4 = tid & 127;
        const int rodd = tid >> 7;
        for (int it = 0; it < 64; ++it) {
            const int r = 2 * it + rodd;
            const int bk = bestk[r];
            const float4 q = ((const float4*)(embed + (size_t)bk * D))[f4];
            ((float4*)(out_q + (size_t)(row0 + r) * D))[f4] = q;
            const float4 xv = ((const float4*)(x + (size_t)(row0 + r) * D))[f4];
            float* sdst = embed_sum + (size_t)bk * D + f4 * 4;
            atomicAdd(sdst + 0, xv.x);
            atomicAdd(sdst + 1, xv.y);
            atomicAdd(sdst + 2, xv.z);
            atomicAdd(sdst + 3, xv.w);
        }
    }
}

// ---------------------------------------------------------------------------
// Exact fp32 rescore of flagged (near-tie) rows; repairs all side effects.
__global__ __launch_bounds__(256) void fixup(const float* __restrict__ x,
                                             const float* __restrict__ embed,
                                             const float* __restrict__ e2,
                                             const int* __restrict__ nflag,
                                             const int* __restrict__ flags,
                                             float* __restrict__ out_ind,
                                             float* __restrict__ out_q,
                                             float* __restrict__ counts,
                                             float* __restrict__ embed_sum) {
    __shared__ float xs[D];
    __shared__ float rb[256];
    __shared__ int ri[256];
    __shared__ int s_old, s_new;
    const int tid = threadIdx.x;
    const int n = *nflag;
    for (int fi = blockIdx.x; fi < n; fi += gridDim.x) {
        const int row = flags[fi];
        if (tid < 128) ((float4*)xs)[tid] = ((const float4*)(x + (size_t)row * D))[tid];
        __syncthreads();
        float best = -3.4e38f; int bi = 0;
        #pragma unroll
        for (int j = 0; j < 4; ++j) {
            const int c = tid * 4 + j;
            float acc = 0.f;
            const float4* ep = (const float4*)(embed + (size_t)c * D);
            for (int i4 = 0; i4 < 128; ++i4) {
                const float4 ev = ep[i4];
                const float4 xv = ((const float4*)xs)[i4];
                acc = fmaf(ev.x, xv.x, acc);
                acc = fmaf(ev.y, xv.y, acc);
                acc = fmaf(ev.z, xv.z, acc);
                acc = fmaf(ev.w, xv.w, acc);
            }
            const float sc = fmaf(-0.5f, e2[c], acc);
            if (sc > best) { best = sc; bi = c; }
        }
        rb[tid] = best; ri[tid] = bi;
        __syncthreads();
        for (int off = 128; off; off >>= 1) {
            if (tid < off) {
                if (rb[tid + off] > rb[tid] ||
                    (rb[tid + off] == rb[tid] && ri[tid + off] < ri[tid])) {
                    rb[tid] = rb[tid + off]; ri[tid] = ri[tid + off];
                }
            }
            __syncthreads();
        }
        if (tid == 0) {
            const int newi = ri[0];
            const int oldi = (int)out_ind[row];
            s_old = oldi;
            s_new = (newi == oldi) ? -1 : newi;
            if (newi != oldi) {
                out_ind[row] = (float)newi;
                atomicAdd(counts + oldi, -1.0f);
                atomicAdd(counts + newi, 1.0f);
            }
        }
        __syncthreads();
        const int nw = s_new;
        if (nw >= 0 && tid < 128) {
            const int ol = s_old;
            const float4 q = ((const float4*)(embed + (size_t)nw * D))[tid];
            ((float4*)(out_q + (size_t)row * D))[tid] = q;
            const float4 xv = ((const float4*)xs)[tid];
            float* so = embed_sum + (size_t)ol * D + tid * 4;
            float* sn = embed_sum + (size_t)nw * D + tid * 4;
            atomicAdd(so + 0, -xv.x); atomicAdd(sn + 0, xv.x);
            atomicAdd(so + 1, -xv.y); atomicAdd(sn + 1, xv.y);
            atomicAdd(so + 2, -xv.z); atomicAdd(sn + 2, xv.z);
            atomicAdd(so + 3, -xv.w); atomicAdd(sn + 3, xv.w);
        }
        __syncthreads();
    }
}

// ---------------------------------------------------------------------------
__global__ __launch_bounds__(256) void ema_cs(const float* __restrict__ cs,
                                              const float* __restrict__ counts,
                                              float* __restrict__ out_cs,
                                              float* __restrict__ nout) {
    __shared__ float red[256];
    const int t = threadIdx.x;
    const float4 c4 = ((const float4*)counts)[t];
    const float4 s4 = ((const float4*)cs)[t];
    float4 nc;
    nc.x = s4.x * DECAY + (1.f - DECAY) * c4.x;
    nc.y = s4.y * DECAY + (1.f - DECAY) * c4.y;
    nc.z = s4.z * DECAY + (1.f - DECAY) * c4.z;
    nc.w = s4.w * DECAY + (1.f - DECAY) * c4.w;
    ((float4*)out_cs)[t] = nc;
    red[t] = nc.x + nc.y + nc.z + nc.w;
    __syncthreads();
    #pragma unroll
    for (int off = 128; off; off >>= 1) {
        if (t < off) red[t] += red[t + off];
        __syncthreads();
    }
    if (t == 0) nout[0] = red[0];
}

// ---------------------------------------------------------------------------
__global__ __launch_bounds__(256) void ema_embed(const float* __restrict__ eavg,
                                                 const float* __restrict__ esum,
                                                 const float* __restrict__ ncs,
                                                 const float* __restrict__ nptr,
                                                 float* __restrict__ out_avg,
                                                 float* __restrict__ out_embed) {
    const int i4 = blockIdx.x * 256 + threadIdx.x;
    const int k = i4 >> 7;
    const float n = *nptr;
    const float csk = (ncs[k] + EPS) / (n + (float)K_CODES * EPS) * n;
    const float inv = 1.f / csk;
    const float4 a = ((const float4*)eavg)[i4];
    const float4 s = ((const float4*)esum)[i4];
    float4 na;
    na.x = a.x * DECAY + (1.f - DECAY) * s.x;
    na.y = a.y * DECAY + (1.f - DECAY) * s.y;
    na.z = a.z * DECAY + (1.f - DECAY) * s.z;
    na.w = a.w * DECAY + (1.f - DECAY) * s.w;
    ((float4*)out_avg)[i4] = na;
    float4 ne;
    ne.x = na.x * inv; ne.y = na.y * inv; ne.z = na.z * inv; ne.w = na.w * inv;
    ((float4*)out_embed)[i4] = ne;
}

// ---------------------------------------------------------------------------
// Fallback f32 vq_main (round-2 proven path) if ws is too small.
#define MT2 128
#define S_STRIDE 132
__global__ __launch_bounds__(256, 2) void vq_main_f32(const float* __restrict__ x,
                                                      const float* __restrict__ embed,
                                                      const float* __restrict__ e2,
                                                      float* __restrict__ out_q,
                                                      float* __restrict__ out_ind,
                                                      float* __restrict__ counts,
                                                      float* __restrict__ embed_sum) {
    __shared__ float xs[32][S_STRIDE];
    __shared__ float es[32][S_STRIDE];
    __shared__ float rsc[MT2][17];
    __shared__ int rid[MT2][17];
    __shared__ int bestk[MT2];
    const int tid = threadIdx.x;
    const int lane = tid & 63;
    const int w = tid >> 6;
    const int tyg = (w & 1) * 8 + (lane >> 3);
    const int txg = (w >> 1) * 8 + (lane & 7);
    const int r0 = 8 * tyg, c0 = 8 * txg;
    const int row0 = blockIdx.x * MT2;
    const int sr = tid >> 3, sq = tid & 7;
    float best_s[8]; int best_i[8];
    #pragma unroll
    for (int r = 0; r < 8; ++r) { best_s[r] = -3.4e38f; best_i[r] = 0; }
    float4 px[4], pe[4];
    #pragma unroll
    for (int i = 0; i < 4; ++i) {
        px[i] = *(const float4*)(x + (size_t)(row0 + sr + 32 * i) * D + sq * 4);
        pe[i] = *(const float4*)(embed + (size_t)(sr + 32 * i) * D + sq * 4);
    }
    for (int kt = 0; kt < 8; ++kt) {
        const int k0 = kt * 128;
        float acc[8][8];
        #pragma unroll
        for (int j = 0; j < 8; ++j) {
            const float he = -0.5f * e2[k0 + c0 + j];
            #pragma unroll
            for (int r = 0; r < 8; ++r) acc[r][j] = he;
        }
        for (int dt = 0; dt < 16; ++dt) {
            __syncthreads();
            #pragma unroll
            for (int i = 0; i < 4; ++i) {
                const int rr = sr + 32 * i;
                #pragma unroll
                for (int ii = 0; ii < 4; ++ii) {
                    xs[sq * 4 + ii][rr] = ((const float*)&px[i])[ii];
                    es[sq * 4 + ii][rr] = ((const float*)&pe[i])[ii];
                }
            }
            __syncthreads();
            {
                const int s2 = kt * 16 + dt + 1;
                int kt2 = s2 >> 4; if (kt2 > 7) kt2 = 7;
                const int dt2 = s2 & 15;
                const int dof = dt2 * 32 + sq * 4;
                #pragma unroll
                for (int i = 0; i < 4; ++i) {
                    px[i] = *(const float4*)(x + (size_t)(row0 + sr + 32 * i) * D + dof);
                    pe[i] = *(const float4*)(embed + (size_t)(kt2 * 128 + sr + 32 * i) * D + dof);
                }
            }
            #pragma unroll 4
            for (int d = 0; d < 32; ++d) {
                const float4 xa = *(const float4*)&xs[d][r0];
                const float4 xb = *(const float4*)&xs[d][r0 + 4];
                const float4 ea = *(const float4*)&es[d][c0];
                const float4 eb = *(const float4*)&es[d][c0 + 4];
                const float xv[8] = {xa.x, xa.y, xa.z, xa.w, xb.x, xb.y, xb.z, xb.w};
                const float evv[8] = {ea.x, ea.y, ea.z, ea.w, eb.x, eb.y, eb.z, eb.w};
                #pragma unroll
                for (int r = 0; r < 8; ++r)
                    #pragma unroll
                    for (int j = 0; j < 8; ++j)
                        acc[r][j] = fmaf(xv[r], evv[j], acc[r][j]);
            }
        }
        #pragma unroll
        for (int j = 0; j < 8; ++j) {
            const int k = k0 + c0 + j;
            #pragma unroll
            for (int r = 0; r < 8; ++r)
                if (acc[r][j] > best_s[r]) { best_s[r] = acc[r][j]; best_i[r] = k; }
        }
    }
    #pragma unroll
    for (int r = 0; r < 8; ++r) { rsc[r0 + r][txg] = best_s[r]; rid[r0 + r][txg] = best_i[r]; }
    __syncthreads();
    if (tid < MT2) {
        float bs = rsc[tid][0]; int bk = rid[tid][0];
        #pragma unroll
        for (int g = 1; g < 16; ++g) {
            const float s = rsc[tid][g]; const int kk = rid[tid][g];
            if (s > bs || (s == bs && kk < bk)) { bs = s; bk = kk; }
        }
        bestk[tid] = bk;
        out_ind[row0 + tid] = (float)bk;
        atomicAdd(counts + bk, 1.0f);
    }
    __syncthreads();
    {
        const int f4 = tid & 127, rodd = tid >> 7;
        for (int it = 0; it < 64; ++it) {
            const int r = 2 * it + rodd;
            const int bk = bestk[r];
            const float4 q = ((const float4*)(embed + (size_t)bk * D))[f4];
            ((float4*)(out_q + (size_t)(row0 + r) * D))[f4] = q;
            const float4 xv = ((const float4*)(x + (size_t)(row0 + r) * D))[f4];
            float* sdst = embed_sum + (size_t)bk * D + f4 * 4;
            atomicAdd(sdst + 0, xv.x);
            atomicAdd(sdst + 1, xv.y);
            atomicAdd(sdst + 2, xv.z);
            atomicAdd(sdst + 3, xv.w);
        }
    }
}

// ---------------------------------------------------------------------------
extern "C" void kernel_launch(void* const* d_in, const int* in_sizes, int n_in,
                              void* d_out, int out_size, void* d_ws, size_t ws_size,
                              hipStream_t stream) {
    const float* x     = (const float*)d_in[0];
    const float* embed = (const float*)d_in[1];
    const float* cs    = (const float*)d_in[2];
    const float* eavg  = (const float*)d_in[3];

    float* out = (float*)d_out;
    float* out_q   = out;
    float* out_ind = out_q + (size_t)N_ROWS * D;
    float* out_cs  = out_ind + N_ROWS;
    float* out_avg = out_cs + K_CODES;
    float* out_emb = out_avg + (size_t)K_CODES * D;

    unsigned char* w = (unsigned char*)d_ws;

    if (ws_size >= WS_NEED) {
        ushort_t* xh = (ushort_t*)(w + XH_OFF);
        ushort_t* xl = (ushort_t*)(w + XL_OFF);
        ushort_t* eh = (ushort_t*)(w + EH_OFF);
        ushort_t* el = (ushort_t*)(w + EL_OFF);
        float* esum  = (float*)(w + ESUM_OFF);
        float* counts = (float*)(w + CNT_OFF);
        float* e2    = (float*)(w + E2_OFF);
        int* nflag   = (int*)(w + NFLAG_OFF);
        float* nptr  = (float*)(w + NPTR_OFF);
        int* flags   = (int*)(w + FLAGS_OFF);

        hipMemsetAsync(esum, 0, 2097152 + 4096, stream);
        hipMemsetAsync(nflag, 0, 4, stream);
        prep_split<<<16384, 256, 0, stream>>>(x, xh, xl);
        prep_split<<<256, 256, 0, stream>>>(embed, eh, el);
        e2_kernel<<<K_CODES, 64, 0, stream>>>(embed, e2);
        vq_main<<<N_ROWS / BM, 256, 0, stream>>>(xh, xl, eh, el, x, embed, e2,
                                                 out_q, out_ind, counts, esum, nflag, flags);
        fixup<<<1024, 256, 0, stream>>>(x, embed, e2, nflag, flags,
                                        out_ind, out_q, counts, esum);
        ema_cs<<<1, 256, 0, stream>>>(cs, counts, out_cs, nptr);
        ema_embed<<<(K_CODES * D / 4) / 256, 256, 0, stream>>>(eavg, esum, out_cs, nptr,
                                                               out_avg, out_emb);
    } else {
        float* counts = (float*)w;
        float* esum = counts + K_CODES;
        float* e2 = esum + (size_t)K_CODES * D;
        float* nptr = e2 + K_CODES;
        hipMemsetAsync(counts, 0, (size_t)(K_CODES + K_CODES * D) * sizeof(float), stream);
        e2_kernel<<<K_CODES, 64, 0, stream>>>(embed, e2);
        vq_main_f32<<<N_ROWS / MT2, 256, 0, stream>>>(x, embed, e2, out_q, out_ind, counts, esum);
        ema_cs<<<1, 256, 0, stream>>>(cs, counts, out_cs, nptr);
        ema_embed<<<(K_CODES * D / 4) / 256, 256, 0, stream>>>(eavg, esum, out_cs, nptr,
                                                               out_avg, out_emb);
    }
}

// Round 2
// 1053.915 us; speedup vs baseline: 1.3671x; 1.3671x over previous
//
#include <hip/hip_runtime.h>

typedef unsigned short ushort_t;
typedef __attribute__((ext_vector_type(8))) short bf16x8;
typedef __attribute__((ext_vector_type(4))) float f32x4;

#define DECAY 0.99f
#define EPS 1e-5f
#define K_CODES 1024
#define D 512
#define N_ROWS 65536
#define MARGIN 0.0625f

// MFMA vq_main tiling: block = 128 rows x 128 codes, BK=32, 4 waves (2x2).
#define BM 128
#define NKT 8          // K_CODES / 128
#define NCH 16         // D / 32 chunks

// ws layout (bytes)
#define XH_OFF   0u
#define XL_OFF   67108864u
#define EH_OFF   134217728u
#define EL_OFF   135266304u
#define ESUM_OFF 136314880u
#define CNT_OFF  138412032u
#define E2_OFF   138416128u
#define NFLAG_OFF 138420224u
#define NPTR_OFF  138420228u
#define FLAGS_OFF 138420480u
#define WS_NEED  (138420480u + 262144u)
// after vq_main, the xh region is dead -> reuse for bucket structures
#define ROWLIST_OFF 0u          // 65536 ints = 256 KB
#define BASE_OFF    262144u     // 1024 ints
#define CURSOR_OFF  266240u     // 1024 ints

// ---------------------------------------------------------------------------
__device__ inline ushort_t f2bf(float f) {
    unsigned int u = __float_as_uint(f);
    unsigned int r = (u + 0x7FFFu + ((u >> 16) & 1u)) >> 16;
    return (ushort_t)r;
}
__device__ inline float bf2f(ushort_t h) { return __uint_as_float(((unsigned int)h) << 16); }

__device__ inline void gload16_lds(const void* g, void* l) {
    __builtin_amdgcn_global_load_lds(
        (const __attribute__((address_space(1))) unsigned int*)g,
        (__attribute__((address_space(3))) unsigned int*)l, 16, 0, 0);
}

// ---------------------------------------------------------------------------
// Split src (f32, rows x 512) into bf16 hi/lo planes in MFMA-fragment-tiled
// order (see round-0 notes).  One thread per 8 elements.
__global__ __launch_bounds__(256) void prep_split(const float* __restrict__ src,
                                                  ushort_t* __restrict__ hi,
                                                  ushort_t* __restrict__ lo) {
    const int g = blockIdx.x * 256 + threadIdx.x;
    const int ln = g & 63;
    const int tc = g >> 6;
    const int C = tc & 15;
    const int R = tc >> 4;
    const int row = (R << 4) + (ln & 15);
    const int k = (C << 5) + ((ln >> 4) << 3);
    const float4 v0 = *(const float4*)(src + (size_t)row * D + k);
    const float4 v1 = *(const float4*)(src + (size_t)row * D + k + 4);
    float v[8] = {v0.x, v0.y, v0.z, v0.w, v1.x, v1.y, v1.z, v1.w};
    short h[8], l[8];
    #pragma unroll
    for (int i = 0; i < 8; ++i) {
        ushort_t hh = f2bf(v[i]);
        h[i] = (short)hh;
        l[i] = (short)f2bf(v[i] - bf2f(hh));
    }
    bf16x8 hv = {h[0], h[1], h[2], h[3], h[4], h[5], h[6], h[7]};
    bf16x8 lv = {l[0], l[1], l[2], l[3], l[4], l[5], l[6], l[7]};
    *(bf16x8*)(hi + (size_t)g * 8) = hv;
    *(bf16x8*)(lo + (size_t)g * 8) = lv;
}

// ---------------------------------------------------------------------------
__global__ __launch_bounds__(64) void e2_kernel(const float* __restrict__ embed,
                                                float* __restrict__ e2) {
    const int k = blockIdx.x;
    const int t = threadIdx.x;
    const float* row = embed + (size_t)k * D;
    float s = 0.f;
    #pragma unroll
    for (int i = 0; i < D / 64; ++i) {
        float v = row[t + 64 * i];
        s = fmaf(v, v, s);
    }
    #pragma unroll
    for (int off = 32; off; off >>= 1) s += __shfl_down(s, off, 64);
    if (t == 0) e2[k] = s;
}

// ---------------------------------------------------------------------------
// MFMA distance + argmax(top2) + quantize gather.  NO embed_sum atomics here
// (embed_sum is built afterwards by bucket + reduce, atomic-free).
__global__ __launch_bounds__(256, 2) void vq_main(const ushort_t* __restrict__ xh,
                                                  const ushort_t* __restrict__ xl,
                                                  const ushort_t* __restrict__ eh,
                                                  const ushort_t* __restrict__ el,
                                                  const float* __restrict__ embed,
                                                  const float* __restrict__ e2,
                                                  float* __restrict__ out_q,
                                                  float* __restrict__ out_ind,
                                                  float* __restrict__ counts,
                                                  int* __restrict__ nflag,
                                                  int* __restrict__ flags) {
    __shared__ short sAh[4096], sAl[4096], sBh[4096], sBl[4096];  // 8KB each
    __shared__ float se2[1024];
    __shared__ float red_b[128][2], red_s[128][2];
    __shared__ int   red_i[128][2];
    __shared__ int   bestk[128];

    const int tid = threadIdx.x;
    const int lane = tid & 63;
    const int w = tid >> 6;
    const int wm = w & 1;       // wave row half
    const int wn = w >> 1;      // wave col half
    const int R0 = blockIdx.x * 8;   // row-tile base (8 row-tiles of 16)
    const int row0 = blockIdx.x * BM;

    for (int i = tid; i < 1024; i += 256) se2[i] = e2[i];

    const int ltile = lane << 3;  // lane*8 shorts = lane*16 B

    float tb[16], ts[16];
    int ti[16];
    #pragma unroll
    for (int s = 0; s < 16; ++s) { tb[s] = -3.4e38f; ts[s] = -3.4e38f; ti[s] = 0; }

    for (int kt = 0; kt < NKT; ++kt) {
        f32x4 acc[4][4];
        #pragma unroll
        for (int mt = 0; mt < 4; ++mt)
            #pragma unroll
            for (int nt = 0; nt < 4; ++nt) acc[mt][nt] = (f32x4){0.f, 0.f, 0.f, 0.f};

        for (int c = 0; c < NCH; ++c) {
            __syncthreads();
            // stage 32 KB: wave 0 -> Ah, 1 -> Al, 2 -> Bh, 3 -> Bl (8 tiles each)
            if (w == 0) {
                #pragma unroll
                for (int t = 0; t < 8; ++t)
                    gload16_lds(xh + ((size_t)((R0 + t) * 16 + c) << 9) + ltile, sAh + (t << 9));
            } else if (w == 1) {
                #pragma unroll
                for (int t = 0; t < 8; ++t)
                    gload16_lds(xl + ((size_t)((R0 + t) * 16 + c) << 9) + ltile, sAl + (t << 9));
            } else if (w == 2) {
                #pragma unroll
                for (int t = 0; t < 8; ++t)
                    gload16_lds(eh + ((size_t)(((kt << 3) + t) * 16 + c) << 9) + ltile, sBh + (t << 9));
            } else {
                #pragma unroll
                for (int t = 0; t < 8; ++t)
                    gload16_lds(el + ((size_t)(((kt << 3) + t) * 16 + c) << 9) + ltile, sBl + (t << 9));
            }
            __syncthreads();

            bf16x8 ah[4], al4[4], bh[4], bl[4];
            #pragma unroll
            for (int i = 0; i < 4; ++i) {
                ah[i]  = *(const bf16x8*)(sAh + (((wm << 2) + i) << 9) + ltile);
                al4[i] = *(const bf16x8*)(sAl + (((wm << 2) + i) << 9) + ltile);
                bh[i]  = *(const bf16x8*)(sBh + (((wn << 2) + i) << 9) + ltile);
                bl[i]  = *(const bf16x8*)(sBl + (((wn << 2) + i) << 9) + ltile);
            }
            #pragma unroll
            for (int nt = 0; nt < 4; ++nt) {
                #pragma unroll
                for (int mt = 0; mt < 4; ++mt) {
                    acc[mt][nt] = __builtin_amdgcn_mfma_f32_16x16x32_bf16(ah[mt], bh[nt], acc[mt][nt], 0, 0, 0);
                    acc[mt][nt] = __builtin_amdgcn_mfma_f32_16x16x32_bf16(al4[mt], bh[nt], acc[mt][nt], 0, 0, 0);
                    acc[mt][nt] = __builtin_amdgcn_mfma_f32_16x16x32_bf16(ah[mt], bl[nt], acc[mt][nt], 0, 0, 0);
                }
            }
        }

        // fold scores of this kt's 64 wave-local codes into per-row top2
        #pragma unroll
        for (int nt = 0; nt < 4; ++nt) {
            const int code = (kt << 7) + (wn << 6) + (nt << 4) + (lane & 15);
            const float h = se2[code];
            #pragma unroll
            for (int mt = 0; mt < 4; ++mt) {
                #pragma unroll
                for (int r = 0; r < 4; ++r) {
                    const float v = fmaf(-0.5f, h, acc[mt][nt][r]);
                    const int s = (mt << 2) + r;
                    if (v > tb[s]) { ts[s] = tb[s]; tb[s] = v; ti[s] = code; }
                    else if (v > ts[s]) ts[s] = v;
                }
            }
        }
    }

    // butterfly merge across the 16 col-lanes (same rows)
    #pragma unroll
    for (int m = 1; m <= 8; m <<= 1) {
        #pragma unroll
        for (int s = 0; s < 16; ++s) {
            const float ob = __shfl_xor(tb[s], m, 64);
            const float os = __shfl_xor(ts[s], m, 64);
            const int oi = __shfl_xor(ti[s], m, 64);
            if (ob > tb[s] || (ob == tb[s] && oi < ti[s])) {
                ts[s] = fmaxf(tb[s], os); tb[s] = ob; ti[s] = oi;
            } else {
                ts[s] = fmaxf(ts[s], ob);
            }
        }
    }
    if ((lane & 15) == 0) {
        const int q = lane >> 4;
        #pragma unroll
        for (int mt = 0; mt < 4; ++mt)
            #pragma unroll
            for (int r = 0; r < 4; ++r) {
                const int rl = wm * 64 + mt * 16 + q * 4 + r;
                const int s = (mt << 2) + r;
                red_b[rl][wn] = tb[s]; red_s[rl][wn] = ts[s]; red_i[rl][wn] = ti[s];
            }
    }
    __syncthreads();

    if (tid < BM) {
        float b0 = red_b[tid][0], b1 = red_b[tid][1];
        float s0 = red_s[tid][0], s1 = red_s[tid][1];
        int i0 = red_i[tid][0], i1 = red_i[tid][1];
        float b, sec; int bi;
        if (b0 > b1 || (b0 == b1 && i0 < i1)) { b = b0; bi = i0; sec = fmaxf(s0, b1); }
        else { b = b1; bi = i1; sec = fmaxf(s1, b0); }
        bestk[tid] = bi;
        out_ind[row0 + tid] = (float)bi;
        atomicAdd(counts + bi, 1.0f);
        if (b - sec < MARGIN) {
            const int p = atomicAdd(nflag, 1);
            flags[p] = row0 + tid;
        }
    }
    __syncthreads();

    // quantize gather only (embed rows are L2-resident)
    {
        const int f4 = tid & 127;
        const int rodd = tid >> 7;
        for (int it = 0; it < 64; ++it) {
            const int r = 2 * it + rodd;
            const int bk = bestk[r];
            const float4 q = ((const float4*)(embed + (size_t)bk * D))[f4];
            ((float4*)(out_q + (size_t)(row0 + r) * D))[f4] = q;
        }
    }
}

// ---------------------------------------------------------------------------
// Exact fp32 rescore of flagged (near-tie) rows; repairs out_ind/out_q/counts.
// (embed_sum is built after this, so nothing to repair there.)
__global__ __launch_bounds__(256) void fixup(const float* __restrict__ x,
                                             const float* __restrict__ embed,
                                             const float* __restrict__ e2,
                                             const int* __restrict__ nflag,
                                             const int* __restrict__ flags,
                                             float* __restrict__ out_ind,
                                             float* __restrict__ out_q,
                                             float* __restrict__ counts) {
    __shared__ float xs[D];
    __shared__ float rb[256];
    __shared__ int ri[256];
    __shared__ int s_new;
    const int tid = threadIdx.x;
    const int n = *nflag;
    for (int fi = blockIdx.x; fi < n; fi += gridDim.x) {
        const int row = flags[fi];
        if (tid < 128) ((float4*)xs)[tid] = ((const float4*)(x + (size_t)row * D))[tid];
        __syncthreads();
        float best = -3.4e38f; int bi = 0;
        #pragma unroll
        for (int j = 0; j < 4; ++j) {
            const int c = tid * 4 + j;
            float acc = 0.f;
            const float4* ep = (const float4*)(embed + (size_t)c * D);
            for (int i4 = 0; i4 < 128; ++i4) {
                const float4 ev = ep[i4];
                const float4 xv = ((const float4*)xs)[i4];
                acc = fmaf(ev.x, xv.x, acc);
                acc = fmaf(ev.y, xv.y, acc);
                acc = fmaf(ev.z, xv.z, acc);
                acc = fmaf(ev.w, xv.w, acc);
            }
            const float sc = fmaf(-0.5f, e2[c], acc);
            if (sc > best) { best = sc; bi = c; }
        }
        rb[tid] = best; ri[tid] = bi;
        __syncthreads();
        for (int off = 128; off; off >>= 1) {
            if (tid < off) {
                if (rb[tid + off] > rb[tid] ||
                    (rb[tid + off] == rb[tid] && ri[tid + off] < ri[tid])) {
                    rb[tid] = rb[tid + off]; ri[tid] = ri[tid + off];
                }
            }
            __syncthreads();
        }
        if (tid == 0) {
            const int newi = ri[0];
            const int oldi = (int)out_ind[row];
            s_new = (newi == oldi) ? -1 : newi;
            if (newi != oldi) {
                out_ind[row] = (float)newi;
                atomicAdd(counts + oldi, -1.0f);
                atomicAdd(counts + newi, 1.0f);
            }
        }
        __syncthreads();
        const int nw = s_new;
        if (nw >= 0 && tid < 128) {
            const float4 q = ((const float4*)(embed + (size_t)nw * D))[tid];
            ((float4*)(out_q + (size_t)row * D))[tid] = q;
        }
        __syncthreads();
    }
}

// ---------------------------------------------------------------------------
// Exclusive prefix sum over 1024 final counts -> base & cursor.
__global__ __launch_bounds__(1024) void scan_kernel(const float* __restrict__ counts,
                                                    int* __restrict__ base,
                                                    int* __restrict__ cursor) {
    __shared__ int s[1024];
    const int t = threadIdx.x;
    const int c = (int)counts[t];
    s[t] = c;
    __syncthreads();
    #pragma unroll
    for (int off = 1; off < 1024; off <<= 1) {
        const int v = (t >= off) ? s[t - off] : 0;
        __syncthreads();
        s[t] += v;
        __syncthreads();
    }
    const int b = s[t] - c;   // exclusive
    base[t] = b;
    cursor[t] = b;
}

// ---------------------------------------------------------------------------
// Bucket row ids by final code. 65536 atomics over 1024 cursors (cheap).
__global__ __launch_bounds__(256) void scatter_kernel(const float* __restrict__ out_ind,
                                                      int* __restrict__ cursor,
                                                      int* __restrict__ rowlist) {
    const int g = blockIdx.x * 256 + threadIdx.x;
    const int code = (int)out_ind[g];
    const int pos = atomicAdd(cursor + code, 1);
    rowlist[pos] = g;
}

// ---------------------------------------------------------------------------
// embed_sum[k] = sum of x rows assigned to code k.  One block per code,
// 128 threads x float4 = full 512-wide row.  Atomic-free, fully overwrites.
__global__ __launch_bounds__(128) void esum_kernel(const float* __restrict__ x,
                                                   const int* __restrict__ base,
                                                   const float* __restrict__ counts,
                                                   const int* __restrict__ rowlist,
                                                   float* __restrict__ embed_sum) {
    const int k = blockIdx.x;
    const int t = threadIdx.x;
    const int b0 = base[k];
    const int cnt = (int)counts[k];
    float4 a0 = {0.f, 0.f, 0.f, 0.f}, a1 = {0.f, 0.f, 0.f, 0.f};
    float4 a2 = {0.f, 0.f, 0.f, 0.f}, a3 = {0.f, 0.f, 0.f, 0.f};
    int i = 0;
    for (; i + 4 <= cnt; i += 4) {
        const int r0 = rowlist[b0 + i];
        const int r1 = rowlist[b0 + i + 1];
        const int r2 = rowlist[b0 + i + 2];
        const int r3 = rowlist[b0 + i + 3];
        const float4 v0 = ((const float4*)x)[(size_t)r0 * 128 + t];
        const float4 v1 = ((const float4*)x)[(size_t)r1 * 128 + t];
        const float4 v2 = ((const float4*)x)[(size_t)r2 * 128 + t];
        const float4 v3 = ((const float4*)x)[(size_t)r3 * 128 + t];
        a0.x += v0.x; a0.y += v0.y; a0.z += v0.z; a0.w += v0.w;
        a1.x += v1.x; a1.y += v1.y; a1.z += v1.z; a1.w += v1.w;
        a2.x += v2.x; a2.y += v2.y; a2.z += v2.z; a2.w += v2.w;
        a3.x += v3.x; a3.y += v3.y; a3.z += v3.z; a3.w += v3.w;
    }
    for (; i < cnt; ++i) {
        const int r = rowlist[b0 + i];
        const float4 v = ((const float4*)x)[(size_t)r * 128 + t];
        a0.x += v.x; a0.y += v.y; a0.z += v.z; a0.w += v.w;
    }
    float4 s;
    s.x = (a0.x + a1.x) + (a2.x + a3.x);
    s.y = (a0.y + a1.y) + (a2.y + a3.y);
    s.z = (a0.z + a1.z) + (a2.z + a3.z);
    s.w = (a0.w + a1.w) + (a2.w + a3.w);
    ((float4*)embed_sum)[(size_t)k * 128 + t] = s;
}

// ---------------------------------------------------------------------------
__global__ __launch_bounds__(256) void ema_cs(const float* __restrict__ cs,
                                              const float* __restrict__ counts,
                                              float* __restrict__ out_cs,
                                              float* __restrict__ nout) {
    __shared__ float red[256];
    const int t = threadIdx.x;
    const float4 c4 = ((const float4*)counts)[t];
    const float4 s4 = ((const float4*)cs)[t];
    float4 nc;
    nc.x = s4.x * DECAY + (1.f - DECAY) * c4.x;
    nc.y = s4.y * DECAY + (1.f - DECAY) * c4.y;
    nc.z = s4.z * DECAY + (1.f - DECAY) * c4.z;
    nc.w = s4.w * DECAY + (1.f - DECAY) * c4.w;
    ((float4*)out_cs)[t] = nc;
    red[t] = nc.x + nc.y + nc.z + nc.w;
    __syncthreads();
    #pragma unroll
    for (int off = 128; off; off >>= 1) {
        if (t < off) red[t] += red[t + off];
        __syncthreads();
    }
    if (t == 0) nout[0] = red[0];
}

// ---------------------------------------------------------------------------
__global__ __launch_bounds__(256) void ema_embed(const float* __restrict__ eavg,
                                                 const float* __restrict__ esum,
                                                 const float* __restrict__ ncs,
                                                 const float* __restrict__ nptr,
                                                 float* __restrict__ out_avg,
                                                 float* __restrict__ out_embed) {
    const int i4 = blockIdx.x * 256 + threadIdx.x;
    const int k = i4 >> 7;
    const float n = *nptr;
    const float csk = (ncs[k] + EPS) / (n + (float)K_CODES * EPS) * n;
    const float inv = 1.f / csk;
    const float4 a = ((const float4*)eavg)[i4];
    const float4 s = ((const float4*)esum)[i4];
    float4 na;
    na.x = a.x * DECAY + (1.f - DECAY) * s.x;
    na.y = a.y * DECAY + (1.f - DECAY) * s.y;
    na.z = a.z * DECAY + (1.f - DECAY) * s.z;
    na.w = a.w * DECAY + (1.f - DECAY) * s.w;
    ((float4*)out_avg)[i4] = na;
    float4 ne;
    ne.x = na.x * inv; ne.y = na.y * inv; ne.z = na.z * inv; ne.w = na.w * inv;
    ((float4*)out_embed)[i4] = ne;
}

// ---------------------------------------------------------------------------
// Fallback f32 vq_main (round-2 proven path) if ws is too small.
#define MT2 128
#define S_STRIDE 132
__global__ __launch_bounds__(256, 2) void vq_main_f32(const float* __restrict__ x,
                                                      const float* __restrict__ embed,
                                                      const float* __restrict__ e2,
                                                      float* __restrict__ out_q,
                                                      float* __restrict__ out_ind,
                                                      float* __restrict__ counts,
                                                      float* __restrict__ embed_sum) {
    __shared__ float xs[32][S_STRIDE];
    __shared__ float es[32][S_STRIDE];
    __shared__ float rsc[MT2][17];
    __shared__ int rid[MT2][17];
    __shared__ int bestk[MT2];
    const int tid = threadIdx.x;
    const int lane = tid & 63;
    const int w = tid >> 6;
    const int tyg = (w & 1) * 8 + (lane >> 3);
    const int txg = (w >> 1) * 8 + (lane & 7);
    const int r0 = 8 * tyg, c0 = 8 * txg;
    const int row0 = blockIdx.x * MT2;
    const int sr = tid >> 3, sq = tid & 7;
    float best_s[8]; int best_i[8];
    #pragma unroll
    for (int r = 0; r < 8; ++r) { best_s[r] = -3.4e38f; best_i[r] = 0; }
    float4 px[4], pe[4];
    #pragma unroll
    for (int i = 0; i < 4; ++i) {
        px[i] = *(const float4*)(x + (size_t)(row0 + sr + 32 * i) * D + sq * 4);
        pe[i] = *(const float4*)(embed + (size_t)(sr + 32 * i) * D + sq * 4);
    }
    for (int kt = 0; kt < 8; ++kt) {
        const int k0 = kt * 128;
        float acc[8][8];
        #pragma unroll
        for (int j = 0; j < 8; ++j) {
            const float he = -0.5f * e2[k0 + c0 + j];
            #pragma unroll
            for (int r = 0; r < 8; ++r) acc[r][j] = he;
        }
        for (int dt = 0; dt < 16; ++dt) {
            __syncthreads();
            #pragma unroll
            for (int i = 0; i < 4; ++i) {
                const int rr = sr + 32 * i;
                #pragma unroll
                for (int ii = 0; ii < 4; ++ii) {
                    xs[sq * 4 + ii][rr] = ((const float*)&px[i])[ii];
                    es[sq * 4 + ii][rr] = ((const float*)&pe[i])[ii];
                }
            }
            __syncthreads();
            {
                const int s2 = kt * 16 + dt + 1;
                int kt2 = s2 >> 4; if (kt2 > 7) kt2 = 7;
                const int dt2 = s2 & 15;
                const int dof = dt2 * 32 + sq * 4;
                #pragma unroll
                for (int i = 0; i < 4; ++i) {
                    px[i] = *(const float4*)(x + (size_t)(row0 + sr + 32 * i) * D + dof);
                    pe[i] = *(const float4*)(embed + (size_t)(kt2 * 128 + sr + 32 * i) * D + dof);
                }
            }
            #pragma unroll 4
            for (int d = 0; d < 32; ++d) {
                const float4 xa = *(const float4*)&xs[d][r0];
                const float4 xb = *(const float4*)&xs[d][r0 + 4];
                const float4 ea = *(const float4*)&es[d][c0];
                const float4 eb = *(const float4*)&es[d][c0 + 4];
                const float xv[8] = {xa.x, xa.y, xa.z, xa.w, xb.x, xb.y, xb.z, xb.w};
                const float evv[8] = {ea.x, ea.y, ea.z, ea.w, eb.x, eb.y, eb.z, eb.w};
                #pragma unroll
                for (int r = 0; r < 8; ++r)
                    #pragma unroll
                    for (int j = 0; j < 8; ++j)
                        acc[r][j] = fmaf(xv[r], evv[j], acc[r][j]);
            }
        }
        #pragma unroll
        for (int j = 0; j < 8; ++j) {
            const int k = k0 + c0 + j;
            #pragma unroll
            for (int r = 0; r < 8; ++r)
                if (acc[r][j] > best_s[r]) { best_s[r] = acc[r][j]; best_i[r] = k; }
        }
    }
    #pragma unroll
    for (int r = 0; r < 8; ++r) { rsc[r0 + r][txg] = best_s[r]; rid[r0 + r][txg] = best_i[r]; }
    __syncthreads();
    if (tid < MT2) {
        float bs = rsc[tid][0]; int bk = rid[tid][0];
        #pragma unroll
        for (int g = 1; g < 16; ++g) {
            const float s = rsc[tid][g]; const int kk = rid[tid][g];
            if (s > bs || (s == bs && kk < bk)) { bs = s; bk = kk; }
        }
        bestk[tid] = bk;
        out_ind[row0 + tid] = (float)bk;
        atomicAdd(counts + bk, 1.0f);
    }
    __syncthreads();
    {
        const int f4 = tid & 127, rodd = tid >> 7;
        for (int it = 0; it < 64; ++it) {
            const int r = 2 * it + rodd;
            const int bk = bestk[r];
            const float4 q = ((const float4*)(embed + (size_t)bk * D))[f4];
            ((float4*)(out_q + (size_t)(row0 + r) * D))[f4] = q;
            const float4 xv = ((const float4*)(x + (size_t)(row0 + r) * D))[f4];
            float* sdst = embed_sum + (size_t)bk * D + f4 * 4;
            atomicAdd(sdst + 0, xv.x);
            atomicAdd(sdst + 1, xv.y);
            atomicAdd(sdst + 2, xv.z);
            atomicAdd(sdst + 3, xv.w);
        }
    }
}

// ---------------------------------------------------------------------------
extern "C" void kernel_launch(void* const* d_in, const int* in_sizes, int n_in,
                              void* d_out, int out_size, void* d_ws, size_t ws_size,
                              hipStream_t stream) {
    const float* x     = (const float*)d_in[0];
    const float* embed = (const float*)d_in[1];
    const float* cs    = (const float*)d_in[2];
    const float* eavg  = (const float*)d_in[3];

    float* out = (float*)d_out;
    float* out_q   = out;
    float* out_ind = out_q + (size_t)N_ROWS * D;
    float* out_cs  = out_ind + N_ROWS;
    float* out_avg = out_cs + K_CODES;
    float* out_emb = out_avg + (size_t)K_CODES * D;

    unsigned char* w = (unsigned char*)d_ws;

    if (ws_size >= WS_NEED) {
        ushort_t* xh = (ushort_t*)(w + XH_OFF);
        ushort_t* xl = (ushort_t*)(w + XL_OFF);
        ushort_t* eh = (ushort_t*)(w + EH_OFF);
        ushort_t* el = (ushort_t*)(w + EL_OFF);
        float* esum  = (float*)(w + ESUM_OFF);
        float* counts = (float*)(w + CNT_OFF);
        float* e2    = (float*)(w + E2_OFF);
        int* nflag   = (int*)(w + NFLAG_OFF);
        float* nptr  = (float*)(w + NPTR_OFF);
        int* flags   = (int*)(w + FLAGS_OFF);
        // bucket structures reuse the xh region (dead after vq_main)
        int* rowlist = (int*)(w + ROWLIST_OFF);
        int* base    = (int*)(w + BASE_OFF);
        int* cursor  = (int*)(w + CURSOR_OFF);

        hipMemsetAsync(counts, 0, 4096, stream);
        hipMemsetAsync(nflag, 0, 4, stream);
        prep_split<<<16384, 256, 0, stream>>>(x, xh, xl);
        prep_split<<<256, 256, 0, stream>>>(embed, eh, el);
        e2_kernel<<<K_CODES, 64, 0, stream>>>(embed, e2);
        vq_main<<<N_ROWS / BM, 256, 0, stream>>>(xh, xl, eh, el, embed, e2,
                                                 out_q, out_ind, counts, nflag, flags);
        fixup<<<1024, 256, 0, stream>>>(x, embed, e2, nflag, flags,
                                        out_ind, out_q, counts);
        scan_kernel<<<1, 1024, 0, stream>>>(counts, base, cursor);
        scatter_kernel<<<N_ROWS / 256, 256, 0, stream>>>(out_ind, cursor, rowlist);
        esum_kernel<<<K_CODES, 128, 0, stream>>>(x, base, counts, rowlist, esum);
        ema_cs<<<1, 256, 0, stream>>>(cs, counts, out_cs, nptr);
        ema_embed<<<(K_CODES * D / 4) / 256, 256, 0, stream>>>(eavg, esum, out_cs, nptr,
                                                               out_avg, out_emb);
    } else {
        float* counts = (float*)w;
        float* esum = counts + K_CODES;
        float* e2 = esum + (size_t)K_CODES * D;
        float* nptr = e2 + K_CODES;
        hipMemsetAsync(counts, 0, (size_t)(K_CODES + K_CODES * D) * sizeof(float), stream);
        e2_kernel<<<K_CODES, 64, 0, stream>>>(embed, e2);
        vq_main_f32<<<N_ROWS / MT2, 256, 0, stream>>>(x, embed, e2, out_q, out_ind, counts, esum);
        ema_cs<<<1, 256, 0, stream>>>(cs, counts, out_cs, nptr);
        ema_embed<<<(K_CODES * D / 4) / 256, 256, 0, stream>>>(eavg, esum, out_cs, nptr,
                                                               out_avg, out_emb);
    }
}

// Round 3
// 743.968 us; speedup vs baseline: 1.9367x; 1.4166x over previous
//
#include <hip/hip_runtime.h>

typedef unsigned short ushort_t;
typedef __attribute__((ext_vector_type(8))) short bf16x8;
typedef __attribute__((ext_vector_type(4))) float f32x4;

#define DECAY 0.99f
#define EPS 1e-5f
#define K_CODES 1024
#define D 512
#define N_ROWS 65536
#define MARGIN 0.0625f

// MFMA vq_main tiling: block = 128 rows x 128 codes, BK=32, 4 waves (2x2).
#define BM 128
#define NKT 8          // K_CODES / 128
#define NCH 16         // D / 32 chunks

// esum chunking
#define CHUNK 64
#define MAX_CHUNKS 2048   // <= K_CODES + N_ROWS/CHUNK

// ws layout (bytes)
#define XH_OFF   0u
#define XL_OFF   67108864u
#define EH_OFF   134217728u
#define EL_OFF   135266304u
#define ESUM_OFF 136314880u
#define CNT_OFF  138412032u
#define E2_OFF   138416128u
#define NFLAG_OFF 138420224u
#define NPTR_OFF  138420228u
#define FLAGS_OFF 138420480u
#define WS_NEED  (138420480u + 262144u)
// after vq_main, the xh region is dead -> reuse for bucket structures
#define ROWLIST_OFF   0u          // 65536 ints = 256 KB
#define BASE_OFF      262144u     // 1024 ints
#define CURSOR_OFF    266240u     // 1024 ints
#define CHUNKBASE_OFF 270336u     // 1025 ints
#define DESC_OFF      274432u     // 2048 * int4 = 32 KB
#define PARTIAL_OFF   307200u     // 2048 * 512 f32 = 4 MiB

// ---------------------------------------------------------------------------
__device__ inline ushort_t f2bf(float f) {
    unsigned int u = __float_as_uint(f);
    unsigned int r = (u + 0x7FFFu + ((u >> 16) & 1u)) >> 16;
    return (ushort_t)r;
}
__device__ inline float bf2f(ushort_t h) { return __uint_as_float(((unsigned int)h) << 16); }

__device__ inline void gload16_lds(const void* g, void* l) {
    __builtin_amdgcn_global_load_lds(
        (const __attribute__((address_space(1))) unsigned int*)g,
        (__attribute__((address_space(3))) unsigned int*)l, 16, 0, 0);
}

// ---------------------------------------------------------------------------
// Split src (f32, rows x 512) into bf16 hi/lo planes in MFMA-fragment-tiled
// order (see round-0 notes).  One thread per 8 elements.
__global__ __launch_bounds__(256) void prep_split(const float* __restrict__ src,
                                                  ushort_t* __restrict__ hi,
                                                  ushort_t* __restrict__ lo) {
    const int g = blockIdx.x * 256 + threadIdx.x;
    const int ln = g & 63;
    const int tc = g >> 6;
    const int C = tc & 15;
    const int R = tc >> 4;
    const int row = (R << 4) + (ln & 15);
    const int k = (C << 5) + ((ln >> 4) << 3);
    const float4 v0 = *(const float4*)(src + (size_t)row * D + k);
    const float4 v1 = *(const float4*)(src + (size_t)row * D + k + 4);
    float v[8] = {v0.x, v0.y, v0.z, v0.w, v1.x, v1.y, v1.z, v1.w};
    short h[8], l[8];
    #pragma unroll
    for (int i = 0; i < 8; ++i) {
        ushort_t hh = f2bf(v[i]);
        h[i] = (short)hh;
        l[i] = (short)f2bf(v[i] - bf2f(hh));
    }
    bf16x8 hv = {h[0], h[1], h[2], h[3], h[4], h[5], h[6], h[7]};
    bf16x8 lv = {l[0], l[1], l[2], l[3], l[4], l[5], l[6], l[7]};
    *(bf16x8*)(hi + (size_t)g * 8) = hv;
    *(bf16x8*)(lo + (size_t)g * 8) = lv;
}

// ---------------------------------------------------------------------------
__global__ __launch_bounds__(64) void e2_kernel(const float* __restrict__ embed,
                                                float* __restrict__ e2) {
    const int k = blockIdx.x;
    const int t = threadIdx.x;
    const float* row = embed + (size_t)k * D;
    float s = 0.f;
    #pragma unroll
    for (int i = 0; i < D / 64; ++i) {
        float v = row[t + 64 * i];
        s = fmaf(v, v, s);
    }
    #pragma unroll
    for (int off = 32; off; off >>= 1) s += __shfl_down(s, off, 64);
    if (t == 0) e2[k] = s;
}

// ---------------------------------------------------------------------------
// MFMA distance + argmax(top2) + quantize gather.  NO embed_sum atomics here
// (embed_sum is built afterwards by bucket + balanced chunk reduce).
__global__ __launch_bounds__(256, 2) void vq_main(const ushort_t* __restrict__ xh,
                                                  const ushort_t* __restrict__ xl,
                                                  const ushort_t* __restrict__ eh,
                                                  const ushort_t* __restrict__ el,
                                                  const float* __restrict__ embed,
                                                  const float* __restrict__ e2,
                                                  float* __restrict__ out_q,
                                                  float* __restrict__ out_ind,
                                                  float* __restrict__ counts,
                                                  int* __restrict__ nflag,
                                                  int* __restrict__ flags) {
    __shared__ short sAh[4096], sAl[4096], sBh[4096], sBl[4096];  // 8KB each
    __shared__ float se2[1024];
    __shared__ float red_b[128][2], red_s[128][2];
    __shared__ int   red_i[128][2];
    __shared__ int   bestk[128];

    const int tid = threadIdx.x;
    const int lane = tid & 63;
    const int w = tid >> 6;
    const int wm = w & 1;       // wave row half
    const int wn = w >> 1;      // wave col half
    const int R0 = blockIdx.x * 8;   // row-tile base (8 row-tiles of 16)
    const int row0 = blockIdx.x * BM;

    for (int i = tid; i < 1024; i += 256) se2[i] = e2[i];

    const int ltile = lane << 3;  // lane*8 shorts = lane*16 B

    float tb[16], ts[16];
    int ti[16];
    #pragma unroll
    for (int s = 0; s < 16; ++s) { tb[s] = -3.4e38f; ts[s] = -3.4e38f; ti[s] = 0; }

    for (int kt = 0; kt < NKT; ++kt) {
        f32x4 acc[4][4];
        #pragma unroll
        for (int mt = 0; mt < 4; ++mt)
            #pragma unroll
            for (int nt = 0; nt < 4; ++nt) acc[mt][nt] = (f32x4){0.f, 0.f, 0.f, 0.f};

        for (int c = 0; c < NCH; ++c) {
            __syncthreads();
            // stage 32 KB: wave 0 -> Ah, 1 -> Al, 2 -> Bh, 3 -> Bl (8 tiles each)
            if (w == 0) {
                #pragma unroll
                for (int t = 0; t < 8; ++t)
                    gload16_lds(xh + ((size_t)((R0 + t) * 16 + c) << 9) + ltile, sAh + (t << 9));
            } else if (w == 1) {
                #pragma unroll
                for (int t = 0; t < 8; ++t)
                    gload16_lds(xl + ((size_t)((R0 + t) * 16 + c) << 9) + ltile, sAl + (t << 9));
            } else if (w == 2) {
                #pragma unroll
                for (int t = 0; t < 8; ++t)
                    gload16_lds(eh + ((size_t)(((kt << 3) + t) * 16 + c) << 9) + ltile, sBh + (t << 9));
            } else {
                #pragma unroll
                for (int t = 0; t < 8; ++t)
                    gload16_lds(el + ((size_t)(((kt << 3) + t) * 16 + c) << 9) + ltile, sBl + (t << 9));
            }
            __syncthreads();

            bf16x8 ah[4], al4[4], bh[4], bl[4];
            #pragma unroll
            for (int i = 0; i < 4; ++i) {
                ah[i]  = *(const bf16x8*)(sAh + (((wm << 2) + i) << 9) + ltile);
                al4[i] = *(const bf16x8*)(sAl + (((wm << 2) + i) << 9) + ltile);
                bh[i]  = *(const bf16x8*)(sBh + (((wn << 2) + i) << 9) + ltile);
                bl[i]  = *(const bf16x8*)(sBl + (((wn << 2) + i) << 9) + ltile);
            }
            #pragma unroll
            for (int nt = 0; nt < 4; ++nt) {
                #pragma unroll
                for (int mt = 0; mt < 4; ++mt) {
                    acc[mt][nt] = __builtin_amdgcn_mfma_f32_16x16x32_bf16(ah[mt], bh[nt], acc[mt][nt], 0, 0, 0);
                    acc[mt][nt] = __builtin_amdgcn_mfma_f32_16x16x32_bf16(al4[mt], bh[nt], acc[mt][nt], 0, 0, 0);
                    acc[mt][nt] = __builtin_amdgcn_mfma_f32_16x16x32_bf16(ah[mt], bl[nt], acc[mt][nt], 0, 0, 0);
                }
            }
        }

        // fold scores of this kt's 64 wave-local codes into per-row top2
        #pragma unroll
        for (int nt = 0; nt < 4; ++nt) {
            const int code = (kt << 7) + (wn << 6) + (nt << 4) + (lane & 15);
            const float h = se2[code];
            #pragma unroll
            for (int mt = 0; mt < 4; ++mt) {
                #pragma unroll
                for (int r = 0; r < 4; ++r) {
                    const float v = fmaf(-0.5f, h, acc[mt][nt][r]);
                    const int s = (mt << 2) + r;
                    if (v > tb[s]) { ts[s] = tb[s]; tb[s] = v; ti[s] = code; }
                    else if (v > ts[s]) ts[s] = v;
                }
            }
        }
    }

    // butterfly merge across the 16 col-lanes (same rows)
    #pragma unroll
    for (int m = 1; m <= 8; m <<= 1) {
        #pragma unroll
        for (int s = 0; s < 16; ++s) {
            const float ob = __shfl_xor(tb[s], m, 64);
            const float os = __shfl_xor(ts[s], m, 64);
            const int oi = __shfl_xor(ti[s], m, 64);
            if (ob > tb[s] || (ob == tb[s] && oi < ti[s])) {
                ts[s] = fmaxf(tb[s], os); tb[s] = ob; ti[s] = oi;
            } else {
                ts[s] = fmaxf(ts[s], ob);
            }
        }
    }
    if ((lane & 15) == 0) {
        const int q = lane >> 4;
        #pragma unroll
        for (int mt = 0; mt < 4; ++mt)
            #pragma unroll
            for (int r = 0; r < 4; ++r) {
                const int rl = wm * 64 + mt * 16 + q * 4 + r;
                const int s = (mt << 2) + r;
                red_b[rl][wn] = tb[s]; red_s[rl][wn] = ts[s]; red_i[rl][wn] = ti[s];
            }
    }
    __syncthreads();

    if (tid < BM) {
        float b0 = red_b[tid][0], b1 = red_b[tid][1];
        float s0 = red_s[tid][0], s1 = red_s[tid][1];
        int i0 = red_i[tid][0], i1 = red_i[tid][1];
        float b, sec; int bi;
        if (b0 > b1 || (b0 == b1 && i0 < i1)) { b = b0; bi = i0; sec = fmaxf(s0, b1); }
        else { b = b1; bi = i1; sec = fmaxf(s1, b0); }
        bestk[tid] = bi;
        out_ind[row0 + tid] = (float)bi;
        atomicAdd(counts + bi, 1.0f);
        if (b - sec < MARGIN) {
            const int p = atomicAdd(nflag, 1);
            flags[p] = row0 + tid;
        }
    }
    __syncthreads();

    // quantize gather only (embed rows are L2-resident)
    {
        const int f4 = tid & 127;
        const int rodd = tid >> 7;
        for (int it = 0; it < 64; ++it) {
            const int r = 2 * it + rodd;
            const int bk = bestk[r];
            const float4 q = ((const float4*)(embed + (size_t)bk * D))[f4];
            ((float4*)(out_q + (size_t)(row0 + r) * D))[f4] = q;
        }
    }
}

// ---------------------------------------------------------------------------
// Exact fp32 rescore of flagged (near-tie) rows; repairs out_ind/out_q/counts.
__global__ __launch_bounds__(256) void fixup(const float* __restrict__ x,
                                             const float* __restrict__ embed,
                                             const float* __restrict__ e2,
                                             const int* __restrict__ nflag,
                                             const int* __restrict__ flags,
                                             float* __restrict__ out_ind,
                                             float* __restrict__ out_q,
                                             float* __restrict__ counts) {
    __shared__ float xs[D];
    __shared__ float rb[256];
    __shared__ int ri[256];
    __shared__ int s_new;
    const int tid = threadIdx.x;
    const int n = *nflag;
    for (int fi = blockIdx.x; fi < n; fi += gridDim.x) {
        const int row = flags[fi];
        if (tid < 128) ((float4*)xs)[tid] = ((const float4*)(x + (size_t)row * D))[tid];
        __syncthreads();
        float best = -3.4e38f; int bi = 0;
        #pragma unroll
        for (int j = 0; j < 4; ++j) {
            const int c = tid * 4 + j;
            float acc = 0.f;
            const float4* ep = (const float4*)(embed + (size_t)c * D);
            for (int i4 = 0; i4 < 128; ++i4) {
                const float4 ev = ep[i4];
                const float4 xv = ((const float4*)xs)[i4];
                acc = fmaf(ev.x, xv.x, acc);
                acc = fmaf(ev.y, xv.y, acc);
                acc = fmaf(ev.z, xv.z, acc);
                acc = fmaf(ev.w, xv.w, acc);
            }
            const float sc = fmaf(-0.5f, e2[c], acc);
            if (sc > best) { best = sc; bi = c; }
        }
        rb[tid] = best; ri[tid] = bi;
        __syncthreads();
        for (int off = 128; off; off >>= 1) {
            if (tid < off) {
                if (rb[tid + off] > rb[tid] ||
                    (rb[tid + off] == rb[tid] && ri[tid + off] < ri[tid])) {
                    rb[tid] = rb[tid + off]; ri[tid] = ri[tid + off];
                }
            }
            __syncthreads();
        }
        if (tid == 0) {
            const int newi = ri[0];
            const int oldi = (int)out_ind[row];
            s_new = (newi == oldi) ? -1 : newi;
            if (newi != oldi) {
                out_ind[row] = (float)newi;
                atomicAdd(counts + oldi, -1.0f);
                atomicAdd(counts + newi, 1.0f);
            }
        }
        __syncthreads();
        const int nw = s_new;
        if (nw >= 0 && tid < 128) {
            const float4 q = ((const float4*)(embed + (size_t)nw * D))[tid];
            ((float4*)(out_q + (size_t)row * D))[tid] = q;
        }
        __syncthreads();
    }
}

// ---------------------------------------------------------------------------
// Exclusive prefix over counts -> base/cursor; chunk prefix -> descriptors.
__global__ __launch_bounds__(1024) void scan_kernel(const float* __restrict__ counts,
                                                    int* __restrict__ base,
                                                    int* __restrict__ cursor,
                                                    int* __restrict__ chunk_base,
                                                    int4* __restrict__ desc) {
    __shared__ int s[1024];
    const int t = threadIdx.x;
    const int c = (int)counts[t];
    s[t] = c;
    __syncthreads();
    #pragma unroll
    for (int off = 1; off < 1024; off <<= 1) {
        const int v = (t >= off) ? s[t - off] : 0;
        __syncthreads();
        s[t] += v;
        __syncthreads();
    }
    const int b = s[t] - c;   // exclusive
    base[t] = b;
    cursor[t] = b;
    // chunk scan
    const int nch = (c + CHUNK - 1) / CHUNK;
    s[t] = nch;
    __syncthreads();
    #pragma unroll
    for (int off = 1; off < 1024; off <<= 1) {
        const int v = (t >= off) ? s[t - off] : 0;
        __syncthreads();
        s[t] += v;
        __syncthreads();
    }
    const int cb = s[t] - nch;  // exclusive
    chunk_base[t] = cb;
    if (t == 1023) chunk_base[1024] = s[t];
    for (int j = 0; j < nch; ++j) {
        const int start = b + j * CHUNK;
        const int len = min(CHUNK, c - j * CHUNK);
        desc[cb + j] = make_int4(t, start, len, 0);
    }
}

// ---------------------------------------------------------------------------
// Bucket row ids by final code. 65536 atomics over 1024 cursors (cheap).
__global__ __launch_bounds__(256) void scatter_kernel(const float* __restrict__ out_ind,
                                                      int* __restrict__ cursor,
                                                      int* __restrict__ rowlist) {
    const int g = blockIdx.x * 256 + threadIdx.x;
    const int code = (int)out_ind[g];
    const int pos = atomicAdd(cursor + code, 1);
    rowlist[pos] = g;
}

// ---------------------------------------------------------------------------
// Balanced partial sums: one block per chunk (<= CHUNK rows each).
__global__ __launch_bounds__(128) void esum_partial(const float* __restrict__ x,
                                                    const int* __restrict__ chunk_base,
                                                    const int4* __restrict__ desc,
                                                    const int* __restrict__ rowlist,
                                                    float* __restrict__ partial) {
    const int b = blockIdx.x;
    if (b >= chunk_base[1024]) return;
    const int t = threadIdx.x;
    const int4 d = desc[b];
    const int b0 = d.y;
    const int cnt = d.z;
    float4 a0 = {0.f, 0.f, 0.f, 0.f}, a1 = {0.f, 0.f, 0.f, 0.f};
    float4 a2 = {0.f, 0.f, 0.f, 0.f}, a3 = {0.f, 0.f, 0.f, 0.f};
    int i = 0;
    for (; i + 4 <= cnt; i += 4) {
        const int r0 = rowlist[b0 + i];
        const int r1 = rowlist[b0 + i + 1];
        const int r2 = rowlist[b0 + i + 2];
        const int r3 = rowlist[b0 + i + 3];
        const float4 v0 = ((const float4*)x)[(size_t)r0 * 128 + t];
        const float4 v1 = ((const float4*)x)[(size_t)r1 * 128 + t];
        const float4 v2 = ((const float4*)x)[(size_t)r2 * 128 + t];
        const float4 v3 = ((const float4*)x)[(size_t)r3 * 128 + t];
        a0.x += v0.x; a0.y += v0.y; a0.z += v0.z; a0.w += v0.w;
        a1.x += v1.x; a1.y += v1.y; a1.z += v1.z; a1.w += v1.w;
        a2.x += v2.x; a2.y += v2.y; a2.z += v2.z; a2.w += v2.w;
        a3.x += v3.x; a3.y += v3.y; a3.z += v3.z; a3.w += v3.w;
    }
    for (; i < cnt; ++i) {
        const int r = rowlist[b0 + i];
        const float4 v = ((const float4*)x)[(size_t)r * 128 + t];
        a0.x += v.x; a0.y += v.y; a0.z += v.z; a0.w += v.w;
    }
    float4 s;
    s.x = (a0.x + a1.x) + (a2.x + a3.x);
    s.y = (a0.y + a1.y) + (a2.y + a3.y);
    s.z = (a0.z + a1.z) + (a2.z + a3.z);
    s.w = (a0.w + a1.w) + (a2.w + a3.w);
    ((float4*)partial)[(size_t)b * 128 + t] = s;
}

// ---------------------------------------------------------------------------
// Reduce each code's chunk partials -> embed_sum (fully overwrites).
__global__ __launch_bounds__(128) void esum_final(const int* __restrict__ chunk_base,
                                                  const float* __restrict__ partial,
                                                  float* __restrict__ embed_sum) {
    const int k = blockIdx.x;
    const int t = threadIdx.x;
    const int c0 = chunk_base[k];
    const int c1 = chunk_base[k + 1];
    float4 a = {0.f, 0.f, 0.f, 0.f};
    for (int c = c0; c < c1; ++c) {
        const float4 v = ((const float4*)partial)[(size_t)c * 128 + t];
        a.x += v.x; a.y += v.y; a.z += v.z; a.w += v.w;
    }
    ((float4*)embed_sum)[(size_t)k * 128 + t] = a;
}

// ---------------------------------------------------------------------------
__global__ __launch_bounds__(256) void ema_cs(const float* __restrict__ cs,
                                              const float* __restrict__ counts,
                                              float* __restrict__ out_cs,
                                              float* __restrict__ nout) {
    __shared__ float red[256];
    const int t = threadIdx.x;
    const float4 c4 = ((const float4*)counts)[t];
    const float4 s4 = ((const float4*)cs)[t];
    float4 nc;
    nc.x = s4.x * DECAY + (1.f - DECAY) * c4.x;
    nc.y = s4.y * DECAY + (1.f - DECAY) * c4.y;
    nc.z = s4.z * DECAY + (1.f - DECAY) * c4.z;
    nc.w = s4.w * DECAY + (1.f - DECAY) * c4.w;
    ((float4*)out_cs)[t] = nc;
    red[t] = nc.x + nc.y + nc.z + nc.w;
    __syncthreads();
    #pragma unroll
    for (int off = 128; off; off >>= 1) {
        if (t < off) red[t] += red[t + off];
        __syncthreads();
    }
    if (t == 0) nout[0] = red[0];
}

// ---------------------------------------------------------------------------
__global__ __launch_bounds__(256) void ema_embed(const float* __restrict__ eavg,
                                                 const float* __restrict__ esum,
                                                 const float* __restrict__ ncs,
                                                 const float* __restrict__ nptr,
                                                 float* __restrict__ out_avg,
                                                 float* __restrict__ out_embed) {
    const int i4 = blockIdx.x * 256 + threadIdx.x;
    const int k = i4 >> 7;
    const float n = *nptr;
    const float csk = (ncs[k] + EPS) / (n + (float)K_CODES * EPS) * n;
    const float inv = 1.f / csk;
    const float4 a = ((const float4*)eavg)[i4];
    const float4 s = ((const float4*)esum)[i4];
    float4 na;
    na.x = a.x * DECAY + (1.f - DECAY) * s.x;
    na.y = a.y * DECAY + (1.f - DECAY) * s.y;
    na.z = a.z * DECAY + (1.f - DECAY) * s.z;
    na.w = a.w * DECAY + (1.f - DECAY) * s.w;
    ((float4*)out_avg)[i4] = na;
    float4 ne;
    ne.x = na.x * inv; ne.y = na.y * inv; ne.z = na.z * inv; ne.w = na.w * inv;
    ((float4*)out_embed)[i4] = ne;
}

// ---------------------------------------------------------------------------
// Fallback f32 vq_main (round-2 proven path) if ws is too small.
#define MT2 128
#define S_STRIDE 132
__global__ __launch_bounds__(256, 2) void vq_main_f32(const float* __restrict__ x,
                                                      const float* __restrict__ embed,
                                                      const float* __restrict__ e2,
                                                      float* __restrict__ out_q,
                                                      float* __restrict__ out_ind,
                                                      float* __restrict__ counts,
                                                      float* __restrict__ embed_sum) {
    __shared__ float xs[32][S_STRIDE];
    __shared__ float es[32][S_STRIDE];
    __shared__ float rsc[MT2][17];
    __shared__ int rid[MT2][17];
    __shared__ int bestk[MT2];
    const int tid = threadIdx.x;
    const int lane = tid & 63;
    const int w = tid >> 6;
    const int tyg = (w & 1) * 8 + (lane >> 3);
    const int txg = (w >> 1) * 8 + (lane & 7);
    const int r0 = 8 * tyg, c0 = 8 * txg;
    const int row0 = blockIdx.x * MT2;
    const int sr = tid >> 3, sq = tid & 7;
    float best_s[8]; int best_i[8];
    #pragma unroll
    for (int r = 0; r < 8; ++r) { best_s[r] = -3.4e38f; best_i[r] = 0; }
    float4 px[4], pe[4];
    #pragma unroll
    for (int i = 0; i < 4; ++i) {
        px[i] = *(const float4*)(x + (size_t)(row0 + sr + 32 * i) * D + sq * 4);
        pe[i] = *(const float4*)(embed + (size_t)(sr + 32 * i) * D + sq * 4);
    }
    for (int kt = 0; kt < 8; ++kt) {
        const int k0 = kt * 128;
        float acc[8][8];
        #pragma unroll
        for (int j = 0; j < 8; ++j) {
            const float he = -0.5f * e2[k0 + c0 + j];
            #pragma unroll
            for (int r = 0; r < 8; ++r) acc[r][j] = he;
        }
        for (int dt = 0; dt < 16; ++dt) {
            __syncthreads();
            #pragma unroll
            for (int i = 0; i < 4; ++i) {
                const int rr = sr + 32 * i;
                #pragma unroll
                for (int ii = 0; ii < 4; ++ii) {
                    xs[sq * 4 + ii][rr] = ((const float*)&px[i])[ii];
                    es[sq * 4 + ii][rr] = ((const float*)&pe[i])[ii];
                }
            }
            __syncthreads();
            {
                const int s2 = kt * 16 + dt + 1;
                int kt2 = s2 >> 4; if (kt2 > 7) kt2 = 7;
                const int dt2 = s2 & 15;
                const int dof = dt2 * 32 + sq * 4;
                #pragma unroll
                for (int i = 0; i < 4; ++i) {
                    px[i] = *(const float4*)(x + (size_t)(row0 + sr + 32 * i) * D + dof);
                    pe[i] = *(const float4*)(embed + (size_t)(kt2 * 128 + sr + 32 * i) * D + dof);
                }
            }
            #pragma unroll 4
            for (int d = 0; d < 32; ++d) {
                const float4 xa = *(const float4*)&xs[d][r0];
                const float4 xb = *(const float4*)&xs[d][r0 + 4];
                const float4 ea = *(const float4*)&es[d][c0];
                const float4 eb = *(const float4*)&es[d][c0 + 4];
                const float xv[8] = {xa.x, xa.y, xa.z, xa.w, xb.x, xb.y, xb.z, xb.w};
                const float evv[8] = {ea.x, ea.y, ea.z, ea.w, eb.x, eb.y, eb.z, eb.w};
                #pragma unroll
                for (int r = 0; r < 8; ++r)
                    #pragma unroll
                    for (int j = 0; j < 8; ++j)
                        acc[r][j] = fmaf(xv[r], evv[j], acc[r][j]);
            }
        }
        #pragma unroll
        for (int j = 0; j < 8; ++j) {
            const int k = k0 + c0 + j;
            #pragma unroll
            for (int r = 0; r < 8; ++r)
                if (acc[r][j] > best_s[r]) { best_s[r] = acc[r][j]; best_i[r] = k; }
        }
    }
    #pragma unroll
    for (int r = 0; r < 8; ++r) { rsc[r0 + r][txg] = best_s[r]; rid[r0 + r][txg] = best_i[r]; }
    __syncthreads();
    if (tid < MT2) {
        float bs = rsc[tid][0]; int bk = rid[tid][0];
        #pragma unroll
        for (int g = 1; g < 16; ++g) {
            const float s = rsc[tid][g]; const int kk = rid[tid][g];
            if (s > bs || (s == bs && kk < bk)) { bs = s; bk = kk; }
        }
        bestk[tid] = bk;
        out_ind[row0 + tid] = (float)bk;
        atomicAdd(counts + bk, 1.0f);
    }
    __syncthreads();
    {
        const int f4 = tid & 127, rodd = tid >> 7;
        for (int it = 0; it < 64; ++it) {
            const int r = 2 * it + rodd;
            const int bk = bestk[r];
            const float4 q = ((const float4*)(embed + (size_t)bk * D))[f4];
            ((float4*)(out_q + (size_t)(row0 + r) * D))[f4] = q;
            const float4 xv = ((const float4*)(x + (size_t)(row0 + r) * D))[f4];
            float* sdst = embed_sum + (size_t)bk * D + f4 * 4;
            atomicAdd(sdst + 0, xv.x);
            atomicAdd(sdst + 1, xv.y);
            atomicAdd(sdst + 2, xv.z);
            atomicAdd(sdst + 3, xv.w);
        }
    }
}

// ---------------------------------------------------------------------------
extern "C" void kernel_launch(void* const* d_in, const int* in_sizes, int n_in,
                              void* d_out, int out_size, void* d_ws, size_t ws_size,
                              hipStream_t stream) {
    const float* x     = (const float*)d_in[0];
    const float* embed = (const float*)d_in[1];
    const float* cs    = (const float*)d_in[2];
    const float* eavg  = (const float*)d_in[3];

    float* out = (float*)d_out;
    float* out_q   = out;
    float* out_ind = out_q + (size_t)N_ROWS * D;
    float* out_cs  = out_ind + N_ROWS;
    float* out_avg = out_cs + K_CODES;
    float* out_emb = out_avg + (size_t)K_CODES * D;

    unsigned char* w = (unsigned char*)d_ws;

    if (ws_size >= WS_NEED) {
        ushort_t* xh = (ushort_t*)(w + XH_OFF);
        ushort_t* xl = (ushort_t*)(w + XL_OFF);
        ushort_t* eh = (ushort_t*)(w + EH_OFF);
        ushort_t* el = (ushort_t*)(w + EL_OFF);
        float* esum  = (float*)(w + ESUM_OFF);
        float* counts = (float*)(w + CNT_OFF);
        float* e2    = (float*)(w + E2_OFF);
        int* nflag   = (int*)(w + NFLAG_OFF);
        float* nptr  = (float*)(w + NPTR_OFF);
        int* flags   = (int*)(w + FLAGS_OFF);
        // bucket structures reuse the xh region (dead after vq_main)
        int* rowlist    = (int*)(w + ROWLIST_OFF);
        int* base       = (int*)(w + BASE_OFF);
        int* cursor     = (int*)(w + CURSOR_OFF);
        int* chunk_base = (int*)(w + CHUNKBASE_OFF);
        int4* desc      = (int4*)(w + DESC_OFF);
        float* partial  = (float*)(w + PARTIAL_OFF);

        hipMemsetAsync(counts, 0, 4096, stream);
        hipMemsetAsync(nflag, 0, 4, stream);
        prep_split<<<16384, 256, 0, stream>>>(x, xh, xl);
        prep_split<<<256, 256, 0, stream>>>(embed, eh, el);
        e2_kernel<<<K_CODES, 64, 0, stream>>>(embed, e2);
        vq_main<<<N_ROWS / BM, 256, 0, stream>>>(xh, xl, eh, el, embed, e2,
                                                 out_q, out_ind, counts, nflag, flags);
        fixup<<<1024, 256, 0, stream>>>(x, embed, e2, nflag, flags,
                                        out_ind, out_q, counts);
        scan_kernel<<<1, 1024, 0, stream>>>(counts, base, cursor, chunk_base, desc);
        scatter_kernel<<<N_ROWS / 256, 256, 0, stream>>>(out_ind, cursor, rowlist);
        esum_partial<<<MAX_CHUNKS, 128, 0, stream>>>(x, chunk_base, desc, rowlist, partial);
        esum_final<<<K_CODES, 128, 0, stream>>>(chunk_base, partial, esum);
        ema_cs<<<1, 256, 0, stream>>>(cs, counts, out_cs, nptr);
        ema_embed<<<(K_CODES * D / 4) / 256, 256, 0, stream>>>(eavg, esum, out_cs, nptr,
                                                               out_avg, out_emb);
    } else {
        float* counts = (float*)w;
        float* esum = counts + K_CODES;
        float* e2 = esum + (size_t)K_CODES * D;
        float* nptr = e2 + K_CODES;
        hipMemsetAsync(counts, 0, (size_t)(K_CODES + K_CODES * D) * sizeof(float), stream);
        e2_kernel<<<K_CODES, 64, 0, stream>>>(embed, e2);
        vq_main_f32<<<N_ROWS / MT2, 256, 0, stream>>>(x, embed, e2, out_q, out_ind, counts, esum);
        ema_cs<<<1, 256, 0, stream>>>(cs, counts, out_cs, nptr);
        ema_embed<<<(K_CODES * D / 4) / 256, 256, 0, stream>>>(eavg, esum, out_cs, nptr,
                                                               out_avg, out_emb);
    }
}